// Round 4
// baseline (93.872 us; speedup 1.0000x reference)
//
#include <hip/hip_runtime.h>

// out[n,m] = exp(-0.5 * sum_d (x[n,d]-c[m,d])^2 / s2[m,d]) / sqrt((2pi)^D * prod s2[m,d])
// Fast path (per-center d-uniform variance; true for bench sigma==1):
//   out = exp2( L2E*(x.a) + qc*r2[n] + c0 ),  a = c/s2, qc = -0.5*L2E/s2,
//   c0 = -0.5*L2E*(c.a) - 0.5*(D*log2(2pi) + log2 prod s2),  r2[n] = sum_d x^2
//
// Round 8 theory: rounds 5-7 proved the loop is OPERAND-DELIVERY bound, not
// load-media bound: a uniform ds_read_b128/global broadcast must deliver
// 16B x 64 lanes = 1024B to the RF (~8cyc), so 8 reads/row = 64 cyc of LDS
// pipe feeds only 32 cyc of pk_fma -> ~27us/CU, the invariant plateau seen
// for global (r0), LDS (r1) and failed-scalar (r2) variants alike.
// Fix: register-block K=2 centers per lane (A for m and m+256, 64 pinned
// VGPRs). One x-row broadcast now feeds 128 outputs -> delivery/output
// halves (~13.5us), bound ~= max(delivery 13.5, store 11, VALU ~6).

#define N_  16384
#define M_  1024
#define D_  32
#define NT  32      // rows per tile
#define BLK 256
#define MB  512     // m's per block: thread t owns m=mb*512+t and +256
                    // grid = (2, 512) = 1024 blocks = 4 blocks/CU exactly

typedef float v4f __attribute__((ext_vector_type(4)));
#define PIN(v) asm volatile("" : "+v"(v))

#define L2E_      1.4426950408889634f   // log2(e)
#define LOG2_2PI_ 2.6514961294723187f   // log2(2*pi)

// ---- workspace layout -------------------------------------------------
// At   : v4f [8][M_]   (A[j] for center m at At[j*M_+m])  128 KB
// qc   : float [M_]                                         4 KB
// c0f  : float [M_]    (fast-path constant)                 4 KB
// g0   : float [M_]    (general-path constant)              4 KB
// flag : float [M_]    (d-uniform sigma?)                   4 KB
#define WS_NEED (8 * M_ * 16 + 4 * M_ * 4)

__global__ __launch_bounds__(64) void rbf_pre(
    const float* __restrict__ centers, const float* __restrict__ sigma,
    v4f* __restrict__ At, float* __restrict__ qc, float* __restrict__ c0f,
    float* __restrict__ g0, float* __restrict__ flag)
{
    const int m = blockIdx.x * 64 + threadIdx.x;
    const v4f* cg = (const v4f*)(centers + (size_t)m * D_);
    const v4f* sg = (const v4f*)(sigma   + (size_t)m * D_);

    v4f cv[8], s2v[8];
    #pragma unroll
    for (int j = 0; j < 8; ++j) {
        cv[j] = cg[j];
        v4f s = sg[j];
        s2v[j] = s * s;
    }
    const float s2_0 = s2v[0].x;
    bool uf = true;
    float pr = 1.0f;                 // f32 product, same as jnp.prod in ref
    #pragma unroll
    for (int j = 0; j < 8; ++j) {
        #pragma unroll
        for (int e = 0; e < 4; ++e) {
            float v = s2v[j][e];
            uf = uf && (v == s2_0);
            pr *= v;
        }
    }
    const float ld = log2f(pr);

    const float w0 = 1.0f / s2_0;
    float b = 0.f;
    #pragma unroll
    for (int j = 0; j < 8; ++j) {
        v4f a = cv[j] * w0;
        At[(size_t)j * M_ + m] = a;          // m-inner -> coalesced
        b = fmaf(cv[j].x, a.x, b);
        b = fmaf(cv[j].y, a.y, b);
        b = fmaf(cv[j].z, a.z, b);
        b = fmaf(cv[j].w, a.w, b);
    }
    const float g = -0.5f * (D_ * LOG2_2PI_ + ld);
    g0[m]   = g;
    c0f[m]  = fmaf(-0.5f * L2E_, b, g);
    qc[m]   = -0.5f * L2E_ * w0;
    flag[m] = uf ? 1.0f : 0.0f;
}

__global__ __launch_bounds__(BLK, 4) void rbf_main(
    const float* __restrict__ x, const float* __restrict__ centers,
    const float* __restrict__ sigma, float* __restrict__ out,
    const v4f* __restrict__ At, const float* __restrict__ qc,
    const float* __restrict__ c0f, const float* __restrict__ g0,
    const float* __restrict__ flag)
{
    const int tid = threadIdx.x;
    const int m0  = blockIdx.x * MB + tid;        // first center
    const int m1  = m0 + BLK;                     // second center (+256)
    const int n0  = blockIdx.y * NT;

    __shared__ __align__(16) v4f   xsv[NT * D_ / 4];  // 4 KB x-tile
    __shared__ __align__(16) float r2s[NT];           // 128 B

    // Stage x-tile + r2 in one coalesced pass: one v4f per thread
    // (8 lanes per row), 8-lane shuffle reduction for r2.
    {
        const v4f* xg = (const v4f*)(x + (size_t)n0 * D_);
        v4f v = xg[tid];
        xsv[tid] = v;
        float s = fmaf(v.x, v.x, fmaf(v.y, v.y, fmaf(v.z, v.z, v.w * v.w)));
        s += __shfl_xor(s, 1);
        s += __shfl_xor(s, 2);
        s += __shfl_xor(s, 4);
        if ((tid & 7) == 0) r2s[tid >> 3] = s;
    }
    __syncthreads();

    const bool fl = (flag[m0] != 0.0f) && (flag[m1] != 0.0f);   // coalesced
    if (__all((int)fl)) {
        const float qc0 = qc[m0],  qc1 = qc[m1];     // coalesced
        const float c00 = c0f[m0], c01 = c0f[m1];    // coalesced
        v4f A[8], B[8];
        #pragma unroll
        for (int j = 0; j < 8; ++j) {
            A[j] = At[(size_t)j * M_ + m0];          // coalesced x4
            B[j] = At[(size_t)j * M_ + m1];
        }
        // Register barrier: A/B stay VGPR-resident across the loop
        // (round-4 lesson: without it the loads sink into the loop).
        #pragma unroll
        for (int j = 0; j < 8; ++j) { PIN(A[j]); PIN(B[j]); }

        float* o0 = out + (size_t)n0 * M_ + m0;      // m1 output = o0 + BLK

        #pragma unroll 1
        for (int i = 0; i < NT; ++i) {
            const v4f* row = xsv + i * 8;            // uniform addr -> bcast
            v4f p0 = {0,0,0,0}, q0 = {0,0,0,0};      // center m0, 2 chains
            v4f p1 = {0,0,0,0}, q1 = {0,0,0,0};      // center m1, 2 chains
            #pragma unroll
            for (int j = 0; j < 8; j += 2) {
                v4f xa = row[j];                     // ds_read_b128 broadcast
                v4f xb = row[j + 1];
                p0 += xa * A[j];                     // 2x v_pk_fma_f32 each
                q0 += xb * A[j + 1];
                p1 += xa * B[j];
                q1 += xb * B[j + 1];
            }
            float rr = r2s[i];                       // b32 broadcast
            v4f t0 = p0 + q0;
            v4f t1 = p1 + q1;
            float d0 = (t0.x + t0.y) + (t0.z + t0.w);
            float d1 = (t1.x + t1.y) + (t1.z + t1.w);
            float f0 = fmaf(L2E_, d0, fmaf(qc0, rr, c00));
            float f1 = fmaf(L2E_, d1, fmaf(qc1, rr, c01));
            __builtin_nontemporal_store(__builtin_amdgcn_exp2f(f0),
                                        o0 + (size_t)i * M_);
            __builtin_nontemporal_store(__builtin_amdgcn_exp2f(f1),
                                        o0 + (size_t)i * M_ + BLK);
        }
    } else {
        // general path: correct for arbitrary sigma, register-frugal
        #pragma unroll 1
        for (int h = 0; h < 2; ++h) {
            const int mm = (h == 0) ? m0 : m1;
            const float c0 = g0[mm];
            const float* cg = centers + (size_t)mm * D_;
            const float* sg = sigma   + (size_t)mm * D_;
            #pragma unroll 1
            for (int i = 0; i < NT; ++i) {
                const float* xr = (const float*)(xsv) + (size_t)i * D_;
                float a0 = 0.f, a1 = 0.f;
                #pragma unroll
                for (int d = 0; d < D_; d += 2) {
                    float s0 = sg[d], s1 = sg[d + 1];
                    float t0 = xr[d]     - cg[d];
                    float t1 = xr[d + 1] - cg[d + 1];
                    a0 = fmaf(t0 * (1.0f / (s0 * s0)), t0, a0);
                    a1 = fmaf(t1 * (1.0f / (s1 * s1)), t1, a1);
                }
                float f = fmaf(-0.5f * L2E_, a0 + a1, c0);
                out[(size_t)(n0 + i) * M_ + mm] = __builtin_amdgcn_exp2f(f);
            }
        }
    }
}

// ---- monolithic fallback (round-6 kernel) if workspace is too small ----
__global__ __launch_bounds__(BLK, 6) void rbf_mono(
    const float* __restrict__ x, const float* __restrict__ centers,
    const float* __restrict__ sigma, float* __restrict__ out)
{
    const int tid = threadIdx.x;
    const int m   = blockIdx.x * BLK + tid;
    const int n0  = blockIdx.y * NT;

    __shared__ __align__(16) float r2s[NT];
    {
        const v4f* xg = (const v4f*)(x + (size_t)n0 * D_);
        v4f v = xg[tid];
        float s = fmaf(v.x, v.x, fmaf(v.y, v.y, fmaf(v.z, v.z, v.w * v.w)));
        s += __shfl_xor(s, 1);
        s += __shfl_xor(s, 2);
        s += __shfl_xor(s, 4);
        if ((tid & 7) == 0) r2s[tid >> 3] = s;
    }
    __syncthreads();

    float s2_0 = 0.f, ld = 0.f;
    bool uf = true;
    {
        const float* sg = sigma + (size_t)m * D_;
        #pragma unroll
        for (int d = 0; d < D_; ++d) {
            float s  = sg[d];
            float s2 = s * s;
            if (d == 0) s2_0 = s2;
            uf = uf && (s2 == s2_0);
            ld += log2f(s2);
        }
    }

    if (__all((int)uf)) {
        const float w0 = 1.0f / s2_0;
        v4f A[8];
        float b = 0.f;
        {
            const v4f* cg = (const v4f*)(centers + (size_t)m * D_);
            #pragma unroll
            for (int j = 0; j < 8; ++j) {
                v4f c = cg[j];
                v4f a = c * w0;
                A[j] = a;
                b = fmaf(c.x, a.x, b); b = fmaf(c.y, a.y, b);
                b = fmaf(c.z, a.z, b); b = fmaf(c.w, a.w, b);
            }
        }
        #pragma unroll
        for (int j = 0; j < 8; ++j) PIN(A[j]);

        const float c0 = fmaf(-0.5f * L2E_, b, -0.5f * (D_ * LOG2_2PI_ + ld));
        const float qc = -0.5f * L2E_ * w0;
        float* o0 = out + (size_t)n0 * M_ + m;

        #pragma unroll 1
        for (int i = 0; i < NT; ++i) {
            const v4f* row = (const v4f*)(x + (size_t)(n0 + i) * D_);
            v4f p = {0,0,0,0}, q = {0,0,0,0};
            #pragma unroll
            for (int j = 0; j < 8; j += 2) {
                p += row[j]     * A[j];
                q += row[j + 1] * A[j + 1];
            }
            v4f t = p + q;
            float dot = (t.x + t.y) + (t.z + t.w);
            float f   = fmaf(L2E_, dot, fmaf(qc, r2s[i], c0));
            __builtin_nontemporal_store(__builtin_amdgcn_exp2f(f),
                                        o0 + (size_t)i * M_);
        }
    } else {
        const float c0 = -0.5f * (D_ * LOG2_2PI_ + ld);
        const float* cg = centers + (size_t)m * D_;
        const float* sg = sigma   + (size_t)m * D_;
        #pragma unroll 1
        for (int i = 0; i < NT; ++i) {
            const float* xr = x + (size_t)(n0 + i) * D_;
            float a0 = 0.f, a1 = 0.f;
            #pragma unroll
            for (int d = 0; d < D_; d += 2) {
                float s0 = sg[d], s1 = sg[d + 1];
                float t0 = xr[d]     - cg[d];
                float t1 = xr[d + 1] - cg[d + 1];
                a0 = fmaf(t0 * (1.0f / (s0 * s0)), t0, a0);
                a1 = fmaf(t1 * (1.0f / (s1 * s1)), t1, a1);
            }
            float f = fmaf(-0.5f * L2E_, a0 + a1, c0);
            out[(size_t)(n0 + i) * M_ + m] = __builtin_amdgcn_exp2f(f);
        }
    }
}

extern "C" void kernel_launch(void* const* d_in, const int* in_sizes, int n_in,
                              void* d_out, int out_size, void* d_ws, size_t ws_size,
                              hipStream_t stream) {
    const float* x = (const float*)d_in[0];
    const float* c = (const float*)d_in[1];
    const float* s = (const float*)d_in[2];
    float* out = (float*)d_out;

    if (ws_size >= (size_t)WS_NEED && d_ws != nullptr) {
        char*  w    = (char*)d_ws;
        v4f*   At   = (v4f*)w;
        float* qc   = (float*)(w + 8 * M_ * 16);
        float* c0f  = qc  + M_;
        float* g0   = c0f + M_;
        float* flag = g0  + M_;
        rbf_pre<<<dim3(M_ / 64), 64, 0, stream>>>(c, s, At, qc, c0f, g0, flag);
        dim3 grid(M_ / MB, N_ / NT);
        rbf_main<<<grid, BLK, 0, stream>>>(x, c, s, out, At, qc, c0f, g0, flag);
    } else {
        dim3 grid(M_ / BLK, N_ / NT);
        rbf_mono<<<grid, BLK, 0, stream>>>(x, c, s, out);
    }
}

// Round 5
// 90.637 us; speedup vs baseline: 1.0357x; 1.0357x over previous
//
#include <hip/hip_runtime.h>

// out[n,m] = exp(-0.5 * sum_d (x[n,d]-c[m,d])^2 / s2[m,d]) / sqrt((2pi)^D * prod s2[m,d])
// Fast path (per-center d-uniform variance; true for bench sigma==1):
//   out = exp2( L2E*(x.a) + qc*r2[n] + c0 ),  a = c/s2, qc = -0.5*L2E/s2,
//   c0 = -0.5*L2E*(c.a) - 0.5*(D*log2(2pi) + log2 prod s2),  r2[n] = sum_d x^2
//
// Round 9: REVERT to the round-3 configuration (best measured: 90.2 us).
// Round-4's K=2 register blocking halved per-output broadcast traffic and
// REGRESSED (93.9) -> the loop is not operand-delivery bound. Issue-count
// model: ~22 slots/wave-row -> ~5us issue + ~11us store HBM = kernel
// ~13-16us; measured dur_us is dominated by the harness's 256MiB poison
// fills (72-76% HBM peak in rocprof) + noise band +-3us. Restoring the
// best-known kernel; if this reproduces ~90us the session is at the
// harness-visible roofline.

#define N_  16384
#define M_  1024
#define D_  32
#define NT  32      // grid = (4, 512) = 2048 blocks -> up to 8 blocks/CU
#define BLK 256

typedef float v4f __attribute__((ext_vector_type(4)));
#define PIN(v) asm volatile("" : "+v"(v))

#define L2E_      1.4426950408889634f   // log2(e)
#define LOG2_2PI_ 2.6514961294723187f   // log2(2*pi)

// ---- workspace layout -------------------------------------------------
// At   : v4f [8][M_]   (A[j] for lane m at At[j*M_+m])   128 KB
// qc   : float [M_]                                        4 KB
// c0f  : float [M_]    (fast-path constant)                4 KB
// g0   : float [M_]    (general-path constant)             4 KB
// flag : int   [M_]    (d-uniform sigma?)                  4 KB
#define WS_NEED (8 * M_ * 16 + 4 * M_ * 4)

__global__ __launch_bounds__(64) void rbf_pre(
    const float* __restrict__ centers, const float* __restrict__ sigma,
    v4f* __restrict__ At, float* __restrict__ qc, float* __restrict__ c0f,
    float* __restrict__ g0, float* __restrict__ flag)
{
    const int m = blockIdx.x * 64 + threadIdx.x;
    const v4f* cg = (const v4f*)(centers + (size_t)m * D_);
    const v4f* sg = (const v4f*)(sigma   + (size_t)m * D_);

    v4f cv[8], s2v[8];
    #pragma unroll
    for (int j = 0; j < 8; ++j) {
        cv[j] = cg[j];
        v4f s = sg[j];
        s2v[j] = s * s;
    }
    const float s2_0 = s2v[0].x;
    bool uf = true;
    float pr = 1.0f;                 // f32 product, same as jnp.prod in ref
    #pragma unroll
    for (int j = 0; j < 8; ++j) {
        #pragma unroll
        for (int e = 0; e < 4; ++e) {
            float v = s2v[j][e];
            uf = uf && (v == s2_0);
            pr *= v;
        }
    }
    const float ld = log2f(pr);

    const float w0 = 1.0f / s2_0;
    float b = 0.f;
    #pragma unroll
    for (int j = 0; j < 8; ++j) {
        v4f a = cv[j] * w0;
        At[(size_t)j * M_ + m] = a;          // m-inner -> coalesced
        b = fmaf(cv[j].x, a.x, b);
        b = fmaf(cv[j].y, a.y, b);
        b = fmaf(cv[j].z, a.z, b);
        b = fmaf(cv[j].w, a.w, b);
    }
    const float g = -0.5f * (D_ * LOG2_2PI_ + ld);
    g0[m]   = g;
    c0f[m]  = fmaf(-0.5f * L2E_, b, g);
    qc[m]   = -0.5f * L2E_ * w0;
    flag[m] = uf ? 1.0f : 0.0f;
}

__global__ __launch_bounds__(BLK, 6) void rbf_main(
    const float* __restrict__ x, const float* __restrict__ centers,
    const float* __restrict__ sigma, float* __restrict__ out,
    const v4f* __restrict__ At, const float* __restrict__ qc,
    const float* __restrict__ c0f, const float* __restrict__ g0,
    const float* __restrict__ flag)
{
    const int tid = threadIdx.x;
    const int m   = blockIdx.x * BLK + tid;
    const int n0  = blockIdx.y * NT;

    __shared__ __align__(16) float r2s[NT];   // 128 B

    // r2 for the tile's 32 rows: one v4f per thread (8 lanes per row),
    // 8-lane shuffle reduction. Fully coalesced, one pass.
    {
        const v4f* xg = (const v4f*)(x + (size_t)n0 * D_);
        v4f v = xg[tid];
        float s = fmaf(v.x, v.x, fmaf(v.y, v.y, fmaf(v.z, v.z, v.w * v.w)));
        s += __shfl_xor(s, 1);
        s += __shfl_xor(s, 2);
        s += __shfl_xor(s, 4);
        if ((tid & 7) == 0) r2s[tid >> 3] = s;
    }
    __syncthreads();

    const float fl = flag[m];          // coalesced
    if (__all(fl != 0.0f)) {
        const float qcm = qc[m];       // coalesced
        const float c0m = c0f[m];      // coalesced
        v4f A[8];
        #pragma unroll
        for (int j = 0; j < 8; ++j) A[j] = At[(size_t)j * M_ + m];  // coalesced x4
        #pragma unroll
        for (int j = 0; j < 8; ++j) PIN(A[j]);   // keep VGPR-resident (round-4 lesson)

        const v4f* r2v = (const v4f*)r2s;
        float* o0 = out + (size_t)n0 * M_ + m;

        #pragma unroll 1
        for (int i = 0; i < NT; i += 8) {
            v4f ra = r2v[i / 4];        // r2s[i..i+3]
            v4f rb = r2v[i / 4 + 1];    // r2s[i+4..i+7]
            #pragma unroll
            for (int k = 0; k < 8; ++k) {
                // Uniform address off readonly __restrict -> scalar loads.
                const v4f* row = (const v4f*)(x + (size_t)(n0 + i + k) * D_);
                v4f x0 = row[0], x1 = row[1], x2 = row[2], x3 = row[3];
                v4f x4 = row[4], x5 = row[5], x6 = row[6], x7 = row[7];
                v4f p = x0 * A[0];
                v4f q = x1 * A[1];
                p += x2 * A[2];  q += x3 * A[3];   // v_pk_fma_f32, SGPR src
                p += x4 * A[4];  q += x5 * A[5];
                p += x6 * A[6];  q += x7 * A[7];
                v4f t = p + q;
                float dot = (t.x + t.y) + (t.z + t.w);
                float rr  = (k < 4) ? ra[k] : rb[k - 4];   // k is constexpr
                float f   = fmaf(L2E_, dot, fmaf(qcm, rr, c0m));
                __builtin_nontemporal_store(__builtin_amdgcn_exp2f(f),
                                            o0 + (size_t)(i + k) * M_);
            }
        }
    } else {
        // general path: correct for arbitrary sigma, register-frugal
        const float c0 = g0[m];
        const float* cg = centers + (size_t)m * D_;
        const float* sg = sigma   + (size_t)m * D_;
        #pragma unroll 1
        for (int i = 0; i < NT; ++i) {
            const float* xr = x + (size_t)(n0 + i) * D_;
            float a0 = 0.f, a1 = 0.f;
            #pragma unroll
            for (int d = 0; d < D_; d += 2) {
                float s0 = sg[d], s1 = sg[d + 1];
                float t0 = xr[d]     - cg[d];
                float t1 = xr[d + 1] - cg[d + 1];
                a0 = fmaf(t0 * (1.0f / (s0 * s0)), t0, a0);
                a1 = fmaf(t1 * (1.0f / (s1 * s1)), t1, a1);
            }
            float f = fmaf(-0.5f * L2E_, a0 + a1, c0);
            out[(size_t)(n0 + i) * M_ + m] = __builtin_amdgcn_exp2f(f);
        }
    }
}

// ---- monolithic fallback (round-6 kernel) if workspace is too small ----
__global__ __launch_bounds__(BLK, 6) void rbf_mono(
    const float* __restrict__ x, const float* __restrict__ centers,
    const float* __restrict__ sigma, float* __restrict__ out)
{
    const int tid = threadIdx.x;
    const int m   = blockIdx.x * BLK + tid;
    const int n0  = blockIdx.y * NT;

    __shared__ __align__(16) float r2s[NT];
    {
        const v4f* xg = (const v4f*)(x + (size_t)n0 * D_);
        v4f v = xg[tid];
        float s = fmaf(v.x, v.x, fmaf(v.y, v.y, fmaf(v.z, v.z, v.w * v.w)));
        s += __shfl_xor(s, 1);
        s += __shfl_xor(s, 2);
        s += __shfl_xor(s, 4);
        if ((tid & 7) == 0) r2s[tid >> 3] = s;
    }
    __syncthreads();

    float s2_0 = 0.f, ld = 0.f;
    bool uf = true;
    {
        const float* sg = sigma + (size_t)m * D_;
        #pragma unroll
        for (int d = 0; d < D_; ++d) {
            float s  = sg[d];
            float s2 = s * s;
            if (d == 0) s2_0 = s2;
            uf = uf && (s2 == s2_0);
            ld += log2f(s2);
        }
    }

    if (__all((int)uf)) {
        const float w0 = 1.0f / s2_0;
        v4f A[8];
        float b = 0.f;
        {
            const v4f* cg = (const v4f*)(centers + (size_t)m * D_);
            #pragma unroll
            for (int j = 0; j < 8; ++j) {
                v4f c = cg[j];
                v4f a = c * w0;
                A[j] = a;
                b = fmaf(c.x, a.x, b); b = fmaf(c.y, a.y, b);
                b = fmaf(c.z, a.z, b); b = fmaf(c.w, a.w, b);
            }
        }
        #pragma unroll
        for (int j = 0; j < 8; ++j) PIN(A[j]);

        const float c0 = fmaf(-0.5f * L2E_, b, -0.5f * (D_ * LOG2_2PI_ + ld));
        const float qc = -0.5f * L2E_ * w0;
        const v4f* r2v = (const v4f*)r2s;
        float* o0 = out + (size_t)n0 * M_ + m;

        #pragma unroll 1
        for (int i = 0; i < NT; i += 8) {
            v4f ra = r2v[i / 4];
            v4f rb = r2v[i / 4 + 1];
            #pragma unroll
            for (int k = 0; k < 8; ++k) {
                const v4f* row = (const v4f*)(x + (size_t)(n0 + i + k) * D_);
                v4f x0 = row[0], x1 = row[1], x2 = row[2], x3 = row[3];
                v4f x4 = row[4], x5 = row[5], x6 = row[6], x7 = row[7];
                v4f p = x0 * A[0];
                v4f q = x1 * A[1];
                p += x2 * A[2];  q += x3 * A[3];
                p += x4 * A[4];  q += x5 * A[5];
                p += x6 * A[6];  q += x7 * A[7];
                v4f t = p + q;
                float dot = (t.x + t.y) + (t.z + t.w);
                float rr  = (k < 4) ? ra[k] : rb[k - 4];
                float f   = fmaf(L2E_, dot, fmaf(qc, rr, c0));
                __builtin_nontemporal_store(__builtin_amdgcn_exp2f(f),
                                            o0 + (size_t)(i + k) * M_);
            }
        }
    } else {
        const float c0 = -0.5f * (D_ * LOG2_2PI_ + ld);
        const float* cg = centers + (size_t)m * D_;
        const float* sg = sigma   + (size_t)m * D_;
        #pragma unroll 1
        for (int i = 0; i < NT; ++i) {
            const float* xr = x + (size_t)(n0 + i) * D_;
            float a0 = 0.f, a1 = 0.f;
            #pragma unroll
            for (int d = 0; d < D_; d += 2) {
                float s0 = sg[d], s1 = sg[d + 1];
                float t0 = xr[d]     - cg[d];
                float t1 = xr[d + 1] - cg[d + 1];
                a0 = fmaf(t0 * (1.0f / (s0 * s0)), t0, a0);
                a1 = fmaf(t1 * (1.0f / (s1 * s1)), t1, a1);
            }
            float f = fmaf(-0.5f * L2E_, a0 + a1, c0);
            out[(size_t)(n0 + i) * M_ + m] = __builtin_amdgcn_exp2f(f);
        }
    }
}

extern "C" void kernel_launch(void* const* d_in, const int* in_sizes, int n_in,
                              void* d_out, int out_size, void* d_ws, size_t ws_size,
                              hipStream_t stream) {
    const float* x = (const float*)d_in[0];
    const float* c = (const float*)d_in[1];
    const float* s = (const float*)d_in[2];
    float* out = (float*)d_out;

    if (ws_size >= (size_t)WS_NEED && d_ws != nullptr) {
        char*  w    = (char*)d_ws;
        v4f*   At   = (v4f*)w;
        float* qc   = (float*)(w + 8 * M_ * 16);
        float* c0f  = qc  + M_;
        float* g0   = c0f + M_;
        float* flag = g0  + M_;
        rbf_pre<<<dim3(M_ / 64), 64, 0, stream>>>(c, s, At, qc, c0f, g0, flag);
        dim3 grid(M_ / BLK, N_ / NT);
        rbf_main<<<grid, BLK, 0, stream>>>(x, c, s, out, At, qc, c0f, g0, flag);
    } else {
        dim3 grid(M_ / BLK, N_ / NT);
        rbf_mono<<<grid, BLK, 0, stream>>>(x, c, s, out);
    }
}